// Round 1
// baseline (199.813 us; speedup 1.0000x reference)
//
#include <hip/hip_runtime.h>
#include <math.h>

#define INF_DELTA 1e10f
#define RM_EPS 1e-10f

// One 64-lane wave per ray; lane s owns sample s.
// Scan (cumprod) via __shfl_up; reductions via __shfl_xor butterfly.
__global__ __launch_bounds__(256) void raymarch_kernel(
    const float* __restrict__ colors,      // (n_rays, 64, 3)
    const float* __restrict__ densities,   // (n_rays, 64)
    const float* __restrict__ depths,      // (n_rays, 64)
    float* __restrict__ rgb_out,           // (n_rays, 3)
    float* __restrict__ depth_out,         // (n_rays,)
    float* __restrict__ weights_out,       // (n_rays, 64)
    float* __restrict__ trans_out,         // (n_rays,)
    int n_rays)
{
    const int lane = threadIdx.x & 63;
    const int ray  = blockIdx.x * 4 + (threadIdx.x >> 6);
    if (ray >= n_rays) return;

    const long base = (long)ray * 64 + lane;

    // Coalesced loads: lane i reads consecutive addresses.
    const float d        = depths[base];
    const float dens_raw = densities[base];
    const float* cptr = colors + (long)ray * 192 + lane * 3;
    const float c0 = cptr[0], c1 = cptr[1], c2 = cptr[2];

    // delta[s] = depths[s+1] - depths[s]; last = INF_DELTA
    const float d_next = __shfl_down(d, 1, 64);
    const float delta = (lane == 63) ? INF_DELTA : (d_next - d);

    // softplus (SP_BETA = 1), numerically stable
    const float x  = dens_raw;
    const float sp = fmaxf(x, 0.0f) + log1pf(__expf(-fabsf(x)));

    const float alpha = 1.0f - __expf(-delta * sp);
    const float t     = 1.0f - alpha + RM_EPS;

    // Inclusive scan product over 64 lanes (6 shuffle steps)
    float p = t;
    #pragma unroll
    for (int off = 1; off < 64; off <<= 1) {
        const float o = __shfl_up(p, off, 64);
        if (lane >= off) p *= o;
    }
    // Exclusive scan: shift by one, lane 0 gets 1.0
    float trans_excl = __shfl_up(p, 1, 64);
    if (lane == 0) trans_excl = 1.0f;

    const float w      = alpha * trans_excl;
    const float finalT = __shfl(p, 63, 64);   // full product incl. last sample

    weights_out[base] = w;   // coalesced

    // Four wave reductions (rgb x3, depth)
    float s0 = w * c0, s1 = w * c1, s2 = w * c2, s3 = w * d;
    #pragma unroll
    for (int off = 32; off > 0; off >>= 1) {
        s0 += __shfl_xor(s0, off, 64);
        s1 += __shfl_xor(s1, off, 64);
        s2 += __shfl_xor(s2, off, 64);
        s3 += __shfl_xor(s3, off, 64);
    }

    if (lane == 0) {
        rgb_out[(long)ray * 3 + 0] = s0;
        rgb_out[(long)ray * 3 + 1] = s1;
        rgb_out[(long)ray * 3 + 2] = s2;
        depth_out[ray] = s3;
        trans_out[ray] = finalT;
    }
}

extern "C" void kernel_launch(void* const* d_in, const int* in_sizes, int n_in,
                              void* d_out, int out_size, void* d_ws, size_t ws_size,
                              hipStream_t stream) {
    const float* colors    = (const float*)d_in[0];
    const float* densities = (const float*)d_in[1];
    const float* depths    = (const float*)d_in[2];

    const int n_rays = in_sizes[1] / 64;   // densities flat count = n_rays * 64

    float* out      = (float*)d_out;
    float* rgb      = out;                              // n_rays*3
    float* depth_o  = rgb + (long)n_rays * 3;           // n_rays
    float* weights  = depth_o + n_rays;                 // n_rays*64
    float* trans    = weights + (long)n_rays * 64;      // n_rays

    const int blocks = (n_rays + 3) / 4;   // 4 waves (rays) per 256-thread block
    raymarch_kernel<<<blocks, 256, 0, stream>>>(
        colors, densities, depths, rgb, depth_o, weights, trans, n_rays);
}

// Round 3
// 198.110 us; speedup vs baseline: 1.0086x; 1.0086x over previous
//
#include <hip/hip_runtime.h>

#define INF_DELTA 1e10f
#define RM_EPS 1e-10f
#define LOG2E 1.4426950408889634f

// One 64-lane wave per ray; lane s owns sample s.
__global__ __launch_bounds__(256) void raymarch_kernel(
    const float* __restrict__ colors,      // (n_rays, 64, 3)
    const float* __restrict__ densities,   // (n_rays, 64)
    const float* __restrict__ depths,      // (n_rays, 64)
    float* __restrict__ rgb_out,           // (n_rays, 3)
    float* __restrict__ depth_out,         // (n_rays,)
    float* __restrict__ weights_out,       // (n_rays, 64)
    float* __restrict__ trans_out,         // (n_rays,)
    int n_rays)
{
    const int lane = threadIdx.x & 63;
    const int ray  = blockIdx.x * 4 + (threadIdx.x >> 6);
    if (ray >= n_rays) return;

    const long base = (long)ray * 64 + lane;

    // Coalesced loads.
    const float d = depths[base];
    const float x = densities[base];
    const float* cptr = colors + (long)ray * 192 + lane * 3;
    const float c0 = cptr[0], c1 = cptr[1], c2 = cptr[2];

    // delta[s] = depths[s+1] - depths[s]; last = INF_DELTA
    const float d_next = __shfl_down(d, 1, 64);
    const float delta = (lane == 63) ? INF_DELTA : (d_next - d);

    // y = exp(-delta * softplus(x)) via hardware exp2/log2:
    //   log2(1+e^x) = relu(x)*log2e + log2(1 + exp2(-|x|*log2e))
    const float q   = __builtin_amdgcn_exp2f(-__builtin_fabsf(x) * LOG2E);
    const float l2  = __builtin_amdgcn_logf(1.0f + q);          // log2(1+q)
    const float sp2 = __builtin_fmaf(__builtin_fmaxf(x, 0.0f), LOG2E, l2); // log2(1+e^x)
    const float y   = __builtin_amdgcn_exp2f(-delta * sp2);     // exp(-delta*softplus(x))

    const float alpha = 1.0f - y;
    const float t     = y + RM_EPS;

    // Inclusive scan product over 64 lanes (6 shuffle steps)
    float p = t;
    #pragma unroll
    for (int off = 1; off < 64; off <<= 1) {
        const float o = __shfl_up(p, off, 64);
        p *= (lane >= off) ? o : 1.0f;
    }
    // Exclusive scan: shift by one, lane 0 gets 1.0
    float trans_excl = __shfl_up(p, 1, 64);
    if (lane == 0) trans_excl = 1.0f;

    const float w      = alpha * trans_excl;
    const float finalT = __shfl(p, 63, 64);

    weights_out[base] = w;   // coalesced

    // Shared-step reduction of 4 values:
    // stage 1: xor1 + xor2 on all four (each lane then holds quad sums)
    float s0 = w * c0, s1 = w * c1, s2 = w * c2, s3 = w * d;
    #pragma unroll
    for (int off = 1; off <= 2; off <<= 1) {
        s0 += __shfl_xor(s0, off, 64);
        s1 += __shfl_xor(s1, off, 64);
        s2 += __shfl_xor(s2, off, 64);
        s3 += __shfl_xor(s3, off, 64);
    }
    // stage 2: lane keeps channel (lane&3); xor 4,8,16,32 preserves lane&3
    const int sel = lane & 3;
    float v = (sel == 0) ? s0 : (sel == 1) ? s1 : (sel == 2) ? s2 : s3;
    #pragma unroll
    for (int off = 4; off < 64; off <<= 1) {
        v += __shfl_xor(v, off, 64);
    }
    // lane k (k=0..3) holds channel-k total

    if (lane < 3) {
        rgb_out[(long)ray * 3 + lane] = v;
    } else if (lane == 3) {
        depth_out[ray] = v;
    } else if (lane == 4) {
        trans_out[ray] = finalT;
    }
}

extern "C" void kernel_launch(void* const* d_in, const int* in_sizes, int n_in,
                              void* d_out, int out_size, void* d_ws, size_t ws_size,
                              hipStream_t stream) {
    const float* colors    = (const float*)d_in[0];
    const float* densities = (const float*)d_in[1];
    const float* depths    = (const float*)d_in[2];

    const int n_rays = in_sizes[1] / 64;   // densities flat count = n_rays * 64

    float* out      = (float*)d_out;
    float* rgb      = out;                              // n_rays*3
    float* depth_o  = rgb + (long)n_rays * 3;           // n_rays
    float* weights  = depth_o + n_rays;                 // n_rays*64
    float* trans    = weights + (long)n_rays * 64;      // n_rays

    const int blocks = (n_rays + 3) / 4;   // 4 waves (rays) per 256-thread block
    raymarch_kernel<<<blocks, 256, 0, stream>>>(
        colors, densities, depths, rgb, depth_o, weights, trans, n_rays);
}